// Round 16
// baseline (215.457 us; speedup 1.0000x reference)
//
#include <hip/hip_runtime.h>

// MultiHeadAttention: x(4,2048,1024) @ W_attn(1024,3072)+b -> QKV -> causal MHA (16 heads, d=64)
// -> attn @ W_proj(1024,1024)+b. Inputs/outputs FLOAT32; internal compute bf16 MFMA + f32 accum.
//
//   0+1. prep_kernel: convert x -> xb AND transpose W_attn/W_proj -> Wta/Wtp (one launch)
//   2. GEMM1: 256x128 tile, 4 waves (128x64/wave), BK=64 single-buffer gload_lds + XOR swizzle
//   3. flash attention (causal, swapped-MFMA layout, K-tile register double-buffer)
//   4. GEMM2: same kernel -> out (f32)
//
// Port model (fits R4-R15): direct-to-LDS staging saturates at ~11 B/cyc/CU; GEMM time ≈
// staged bytes / 11. 256x128 cuts staged bytes 25% vs 128x128 (B-panel refetched half as
// often); 4 waves (not 8) keeps ~2 resident blocks so compute/barriers hide under the port.

typedef __attribute__((ext_vector_type(8))) __bf16 bf16x8;
typedef __attribute__((ext_vector_type(4))) float f32x4;
typedef __attribute__((ext_vector_type(4))) short s16x4;

__device__ __forceinline__ unsigned short f2bf(float f) {
    unsigned u = __builtin_bit_cast(unsigned, f);
    u += 0x7fffu + ((u >> 16) & 1u);   // RNE
    return (unsigned short)(u >> 16);
}
__device__ __forceinline__ unsigned pack2bf(float a, float b) {
    return (unsigned)f2bf(a) | ((unsigned)f2bf(b) << 16);
}
// async 16B global -> LDS (HW: wave-uniform LDS base + lane*16; global addr per-lane)
__device__ __forceinline__ void gload16(const unsigned short* g, unsigned short* l) {
    __builtin_amdgcn_global_load_lds(
        (const __attribute__((address_space(1))) unsigned int*)g,
        (__attribute__((address_space(3))) unsigned int*)l, 16, 0, 0);
}

// -------- fused prep: blocks [0,8192) convert x f32->bf16; [8192,12288) transpose weights --------
__global__ void prep_kernel(const float* __restrict__ x, unsigned short* __restrict__ xb,
                            const float* __restrict__ Wa, unsigned short* __restrict__ Wta,
                            const float* __restrict__ Wp, unsigned short* __restrict__ Wtp) {
    __shared__ float t[32][33];
    const int tid = threadIdx.x;
    const int bid = blockIdx.x;
    if (bid < 8192) {
        long i = ((long)bid * 256 + tid) * 4;
        f32x4 v = *reinterpret_cast<const f32x4*>(&x[i]);
        s16x4 o;
        o[0] = (short)f2bf(v[0]);
        o[1] = (short)f2bf(v[1]);
        o[2] = (short)f2bf(v[2]);
        o[3] = (short)f2bf(v[3]);
        *reinterpret_cast<s16x4*>(&xb[i]) = o;
        return;
    }
    int tb = bid - 8192;
    int bx = tb & 127, by = tb >> 7;     // 128 x 32
    const float* W;
    unsigned short* Wt;
    int N;
    if (bx < 96) { W = Wa; Wt = Wta; N = 3072; }
    else         { W = Wp; Wt = Wtp; N = 1024; bx -= 96; }
    const int K = 1024;
    const int n0 = bx * 32, k0 = by * 32;
    const int row = tid >> 3, c4 = (tid & 7) * 4;
    f32x4 v = *reinterpret_cast<const f32x4*>(&W[(size_t)(k0 + row) * N + n0 + c4]);
    t[row][c4 + 0] = v[0];
    t[row][c4 + 1] = v[1];
    t[row][c4 + 2] = v[2];
    t[row][c4 + 3] = v[3];
    __syncthreads();
    s16x4 o;
    o[0] = (short)f2bf(t[c4 + 0][row]);
    o[1] = (short)f2bf(t[c4 + 1][row]);
    o[2] = (short)f2bf(t[c4 + 2][row]);
    o[3] = (short)f2bf(t[c4 + 3][row]);
    *reinterpret_cast<s16x4*>(&Wt[(size_t)(n0 + row) * K + k0 + c4]) = o;
}

// ====== 256x128 tile MFMA GEMM, 4 waves (2Mx2N, 128x64/wave), BK=64 single-buffer gload_lds ======
// Staged bytes/block-step: A 32KB + B 16KB = 48KB (12 gload16/thread). LDS 48KB -> 2 blocks/CU.
// LDS swizzle (R7-proven): stored col-byte = logical ^ ((row&7)<<4); pre-swizzled global source +
// inverted ds_read address -> conflict-free b128 reads.
// MODE 0: C = A @ Bt^T + bias -> Cout (f32). MODE 1: scatter QKV bf16 (Q pre-scaled 0.125).
template <int MODE>
__global__ __launch_bounds__(256, 2)
void gemm_kernel(const unsigned short* __restrict__ A,
                 const unsigned short* __restrict__ Bt,
                 const float* __restrict__ bias,
                 float* __restrict__ Cout,
                 unsigned short* __restrict__ Qo,
                 unsigned short* __restrict__ Ko,
                 unsigned short* __restrict__ Vto,
                 int M, int N, int Kd) {
    __shared__ unsigned short As[256 * 64];   // 32 KB
    __shared__ unsigned short Bs[128 * 64];   // 16 KB
    const int tid = threadIdx.x;
    const int wave = tid >> 6, lane = tid & 63;
    const int l15 = lane & 15, lhi = lane >> 4;
    const int wm = wave >> 1, wn = wave & 1;   // wave tile: rows wm*128..+127, cols wn*64..+63
    const int m0 = blockIdx.x * 256, n0 = blockIdx.y * 128;

    f32x4 acc[8][4];
#pragma unroll
    for (int i = 0; i < 8; i++)
#pragma unroll
        for (int j = 0; j < 4; j++) acc[i][j] = f32x4{0.f, 0.f, 0.f, 0.f};

    // staging: thread t -> row r0 = t>>3 (0..31) + 32*blk, 16B chunk (t&7); pre-swizzled source
    const int r0 = tid >> 3;
    const int cswz = (((tid & 7) ^ (r0 & 7)) << 3);
    const unsigned short* Ap = &A[(size_t)(m0 + r0) * Kd + cswz];
    const unsigned short* Bp = &Bt[(size_t)(n0 + r0) * Kd + cswz];
    const size_t K32 = (size_t)32 * Kd;
    const int csw0 = (lhi * 8) ^ ((l15 & 7) << 3);

    for (int k0 = 0; k0 < Kd; k0 += 64) {
#pragma unroll
        for (int blk = 0; blk < 8; blk++)
            gload16(Ap + blk * K32 + k0, &As[blk * 2048 + tid * 8]);
#pragma unroll
        for (int blk = 0; blk < 4; blk++)
            gload16(Bp + blk * K32 + k0, &Bs[blk * 2048 + tid * 8]);
        __syncthreads();   // drains vmcnt(0): buffer ready

#pragma unroll
        for (int ks = 0; ks < 2; ks++) {
            bf16x8 av[8], bv[4];
#pragma unroll
            for (int i = 0; i < 8; i++)
                av[i] = *reinterpret_cast<const bf16x8*>(
                    &As[(wm * 128 + i * 16 + l15) * 64 + (ks * 32 ^ csw0)]);
#pragma unroll
            for (int j = 0; j < 4; j++)
                bv[j] = *reinterpret_cast<const bf16x8*>(
                    &Bs[(wn * 64 + j * 16 + l15) * 64 + (ks * 32 ^ csw0)]);
#pragma unroll
            for (int i = 0; i < 8; i++)
#pragma unroll
                for (int j = 0; j < 4; j++)
                    acc[i][j] = __builtin_amdgcn_mfma_f32_16x16x32_bf16(av[i], bv[j],
                                                                        acc[i][j], 0, 0, 0);
        }
        __syncthreads();
    }

    // epilogue: D[row=(lane>>4)*4+r][col=lane&15] per 16x16 fragment
#pragma unroll
    for (int j = 0; j < 4; j++) {
        const int col = n0 + wn * 64 + j * 16 + l15;
        const float bv = bias[col];
#pragma unroll
        for (int i = 0; i < 8; i++) {
            const int rbase = m0 + wm * 128 + i * 16 + lhi * 4;
#pragma unroll
            for (int r = 0; r < 4; r++) {
                const int row = rbase + r;
                const float oval = acc[i][j][r] + bv;
                if (MODE == 0) {
                    Cout[(size_t)row * N + col] = oval;
                } else {
                    const int sel = col >> 10, c1 = col & 1023;
                    const int h = c1 >> 6, d = c1 & 63;
                    const int b = row >> 11, t = row & 2047;
                    if (sel == 0)
                        Qo[(((size_t)(b * 16 + h)) * 2048 + t) * 64 + d] = f2bf(oval * 0.125f);
                    else if (sel == 1)
                        Ko[(((size_t)(b * 16 + h)) * 2048 + t) * 64 + d] = f2bf(oval);
                    else
                        Vto[(((size_t)(b * 16 + h)) * 64 + d) * 2048 + t] = f2bf(oval);
                }
            }
        }
    }
}

// ---------------- causal flash attention, swapped-MFMA layout, K prefetch ----------------
// 1 wave = 64 q rows (4 q-frags); block = 4 waves; grid = 512 (head = bid&63).
__global__ __launch_bounds__(256, 2)
void attn_kernel(const unsigned short* __restrict__ Q,
                 const unsigned short* __restrict__ Kg,
                 const unsigned short* __restrict__ Vt,
                 unsigned short* __restrict__ Aout) {
    __shared__ unsigned int Pl[4][16 * 36];     // per-wave P^T tile: [q=16][k=64] bf16, 144B rows
    const int tid = threadIdx.x, wave = tid >> 6, lane = tid & 63;
    const int l15 = lane & 15, lhi = lane >> 4;
    const int bid = blockIdx.x;
    const int head = bid & 63;
    const int j = bid >> 6;
    const int qb = (j < 4) ? j : (11 - j);       // complement pairing: qb(j)+qb(j+4)=7
    const int q0w = qb * 256 + wave * 64;
    const unsigned short* Qh = Q + (size_t)head * (2048 * 64);
    const unsigned short* Kh = Kg + (size_t)head * (2048 * 64);
    const unsigned short* Vh = Vt + (size_t)head * (64 * 2048);
    unsigned int* P = &Pl[wave][0];

    bf16x8 qfr[4][2];
#pragma unroll
    for (int qf = 0; qf < 4; qf++)
#pragma unroll
        for (int dh = 0; dh < 2; dh++)
            qfr[qf][dh] = *reinterpret_cast<const bf16x8*>(
                &Qh[(size_t)(q0w + qf * 16 + l15) * 64 + dh * 32 + lhi * 8]);

    f32x4 o[4][4];   // [df][qf], O^T[d=df*16+lhi*4+r][q=qf*16+l15]
#pragma unroll
    for (int df = 0; df < 4; df++)
#pragma unroll
        for (int qf = 0; qf < 4; qf++) o[df][qf] = f32x4{0.f, 0.f, 0.f, 0.f};
    float m[4] = {-1e30f, -1e30f, -1e30f, -1e30f};
    float l[4] = {0.f, 0.f, 0.f, 0.f};

#define LOADK(DST, kt)                                                                  \
    do {                                                                                \
        _Pragma("unroll") for (int kf = 0; kf < 4; kf++)                                \
            _Pragma("unroll") for (int dh = 0; dh < 2; dh++)                            \
                DST[kf][dh] = *reinterpret_cast<const bf16x8*>(                         \
                    &Kh[(size_t)((kt) + kf * 16 + l15) * 64 + dh * 32 + lhi * 8]);      \
    } while (0)

    const int ntiles = (q0w >> 6) + 1;
    bf16x8 ka[4][2], kb[4][2], vfr[4][2];
    LOADK(ka, 0);
    for (int t = 0; t < ntiles; ++t) {
        const int kt = t * 64;
        const bool masked = (t == ntiles - 1);
#pragma unroll
        for (int df = 0; df < 4; df++)
#pragma unroll
            for (int kc = 0; kc < 2; kc++)
                vfr[df][kc] = *reinterpret_cast<const bf16x8*>(
                    &Vh[(size_t)(df * 16 + l15) * 2048 + kt + kc * 32 + lhi * 8]);
        const int ktn = masked ? kt : kt + 64;
        LOADK(kb, ktn);

#pragma unroll
        for (int qf = 0; qf < 4; qf++) {
            f32x4 s[4];
#pragma unroll
            for (int kf = 0; kf < 4; kf++) {
                s[kf] = __builtin_amdgcn_mfma_f32_16x16x32_bf16(ka[kf][0], qfr[qf][0],
                                                                f32x4{0.f, 0.f, 0.f, 0.f}, 0, 0, 0);
                s[kf] = __builtin_amdgcn_mfma_f32_16x16x32_bf16(ka[kf][1], qfr[qf][1], s[kf], 0, 0, 0);
            }
            if (masked) {
#pragma unroll
                for (int kf = 0; kf < 4; kf++)
#pragma unroll
                    for (int r = 0; r < 4; r++)
                        if (kf * 16 + lhi * 4 + r > qf * 16 + l15) s[kf][r] = -1e30f;
            }
            float tm = s[0][0];
#pragma unroll
            for (int kf = 0; kf < 4; kf++)
#pragma unroll
                for (int r = 0; r < 4; r++) tm = fmaxf(tm, s[kf][r]);
            tm = fmaxf(tm, __shfl_xor(tm, 16));
            tm = fmaxf(tm, __shfl_xor(tm, 32));
            const float mn = fmaxf(m[qf], tm);
            const float corr = __expf(m[qf] - mn);
            m[qf] = mn;
            float rs = 0.f;
#pragma unroll
            for (int kf = 0; kf < 4; kf++)
#pragma unroll
                for (int r = 0; r < 4; r++) {
                    const float p = __expf(s[kf][r] - mn);
                    s[kf][r] = p;
                    rs += p;
                }
            rs += __shfl_xor(rs, 16);
            rs += __shfl_xor(rs, 32);
            l[qf] = l[qf] * corr + rs;
#pragma unroll
            for (int df = 0; df < 4; df++)
#pragma unroll
                for (int r = 0; r < 4; r++) o[df][qf][r] *= corr;

#pragma unroll
            for (int kf = 0; kf < 4; kf++) {
                P[l15 * 36 + kf * 8 + lhi * 2 + 0] = pack2bf(s[kf][0], s[kf][1]);
                P[l15 * 36 + kf * 8 + lhi * 2 + 1] = pack2bf(s[kf][2], s[kf][3]);
            }
            asm volatile("s_waitcnt lgkmcnt(0)" ::: "memory");
            bf16x8 pb0 = *reinterpret_cast<const bf16x8*>(&P[l15 * 36 + 0 * 16 + lhi * 4]);
            bf16x8 pb1 = *reinterpret_cast<const bf16x8*>(&P[l15 * 36 + 1 * 16 + lhi * 4]);
#pragma unroll
            for (int df = 0; df < 4; df++) {
                o[df][qf] = __builtin_amdgcn_mfma_f32_16x16x32_bf16(vfr[df][0], pb0, o[df][qf], 0, 0, 0);
                o[df][qf] = __builtin_amdgcn_mfma_f32_16x16x32_bf16(vfr[df][1], pb1, o[df][qf], 0, 0, 0);
            }
        }
#pragma unroll
        for (int kf = 0; kf < 4; kf++)
#pragma unroll
            for (int dh = 0; dh < 2; dh++) ka[kf][dh] = kb[kf][dh];
    }
#undef LOADK

    const int b = head >> 4, h = head & 15;
#pragma unroll
    for (int qf = 0; qf < 4; qf++) {
        const float inv = 1.0f / l[qf];
        unsigned short* op = Aout + ((size_t)(b * 2048 + q0w + qf * 16 + l15)) * 1024 + h * 64;
#pragma unroll
        for (int df = 0; df < 4; df++) {
            *reinterpret_cast<unsigned*>(&op[df * 16 + lhi * 4]) =
                pack2bf(o[df][qf][0] * inv, o[df][qf][1] * inv);
            *reinterpret_cast<unsigned*>(&op[df * 16 + lhi * 4 + 2]) =
                pack2bf(o[df][qf][2] * inv, o[df][qf][3] * inv);
        }
    }
}

extern "C" void kernel_launch(void* const* d_in, const int* in_sizes, int n_in,
                              void* d_out, int out_size, void* d_ws, size_t ws_size,
                              hipStream_t stream) {
    const float* x     = (const float*)d_in[0];
    const float* Wattn = (const float*)d_in[1];
    const float* battn = (const float*)d_in[2];
    const float* Wproj = (const float*)d_in[3];
    const float* bproj = (const float*)d_in[4];
    float* out = (float*)d_out;

    unsigned short* ws = (unsigned short*)d_ws;
    const size_t HS = (size_t)4 * 16 * 2048 * 64;
    unsigned short* Qb  = ws;
    unsigned short* Kb  = Qb + HS;
    unsigned short* Vtb = Kb + HS;
    unsigned short* Ab  = Vtb + HS;
    unsigned short* Wta = Ab + HS;
    unsigned short* Wtp = Wta + (size_t)3072 * 1024;
    unsigned short* xb  = Wtp + (size_t)1024 * 1024;

    prep_kernel<<<12288, 256, 0, stream>>>(x, xb, Wattn, Wta, Wproj, Wtp);
    gemm_kernel<1><<<dim3(32, 24), 256, 0, stream>>>(xb, Wta, battn, nullptr, Qb, Kb, Vtb,
                                                     8192, 3072, 1024);
    attn_kernel<<<512, 256, 0, stream>>>(Qb, Kb, Vtb, Ab);
    gemm_kernel<0><<<dim3(32, 8), 256, 0, stream>>>(Ab, Wtp, bproj, out, nullptr, nullptr, nullptr,
                                                    8192, 1024, 1024);
}

// Round 17
// 195.422 us; speedup vs baseline: 1.1025x; 1.1025x over previous
//
#include <hip/hip_runtime.h>

// MultiHeadAttention: x(4,2048,1024) @ W_attn(1024,3072)+b -> QKV -> causal MHA (16 heads, d=64)
// -> attn @ W_proj(1024,1024)+b. Inputs/outputs FLOAT32; internal compute bf16 MFMA + f32 accum.
//
//   0+1. prep_kernel (fused): convert x -> xb AND transpose W_attn/W_proj -> Wta/Wtp
//   2. GEMM1: 128x128 BK=64 single-buffer gload_lds + both-sides XOR swizzle (session-best)
//   3. flash attention (causal, swapped-MFMA layout, K-tile register double-buffer)
//   4. GEMM2: same kernel -> out (f32)
//
// Session consolidation: R14 GEMM config (197.2us best) + R16 fused prep + R12 attn.
// Structure-space findings: 128^2/BK=64/4-wave is the residency-coverage optimum; larger
// tiles (R6/R11/R16), dbuf (R5), counted-vmcnt (R8), XCD supertiles (R9), 8-wave (R13/R15),
// occupancy bounds (R14) all <= neutral. GEMM staging path ~11 B/cyc/CU is the binding wall.

typedef __attribute__((ext_vector_type(8))) __bf16 bf16x8;
typedef __attribute__((ext_vector_type(4))) float f32x4;
typedef __attribute__((ext_vector_type(4))) short s16x4;

__device__ __forceinline__ unsigned short f2bf(float f) {
    unsigned u = __builtin_bit_cast(unsigned, f);
    u += 0x7fffu + ((u >> 16) & 1u);   // RNE
    return (unsigned short)(u >> 16);
}
__device__ __forceinline__ unsigned pack2bf(float a, float b) {
    return (unsigned)f2bf(a) | ((unsigned)f2bf(b) << 16);
}
// async 16B global -> LDS (HW: wave-uniform LDS base + lane*16; global addr per-lane)
__device__ __forceinline__ void gload16(const unsigned short* g, unsigned short* l) {
    __builtin_amdgcn_global_load_lds(
        (const __attribute__((address_space(1))) unsigned int*)g,
        (__attribute__((address_space(3))) unsigned int*)l, 16, 0, 0);
}

// -------- fused prep: blocks [0,8192) convert x f32->bf16; [8192,12288) transpose weights --------
__global__ void prep_kernel(const float* __restrict__ x, unsigned short* __restrict__ xb,
                            const float* __restrict__ Wa, unsigned short* __restrict__ Wta,
                            const float* __restrict__ Wp, unsigned short* __restrict__ Wtp) {
    __shared__ float t[32][33];
    const int tid = threadIdx.x;
    const int bid = blockIdx.x;
    if (bid < 8192) {
        long i = ((long)bid * 256 + tid) * 4;
        f32x4 v = *reinterpret_cast<const f32x4*>(&x[i]);
        s16x4 o;
        o[0] = (short)f2bf(v[0]);
        o[1] = (short)f2bf(v[1]);
        o[2] = (short)f2bf(v[2]);
        o[3] = (short)f2bf(v[3]);
        *reinterpret_cast<s16x4*>(&xb[i]) = o;
        return;
    }
    int tb = bid - 8192;
    int bx = tb & 127, by = tb >> 7;     // 128 x 32
    const float* W;
    unsigned short* Wt;
    int N;
    if (bx < 96) { W = Wa; Wt = Wta; N = 3072; }
    else         { W = Wp; Wt = Wtp; N = 1024; bx -= 96; }
    const int K = 1024;
    const int n0 = bx * 32, k0 = by * 32;
    const int row = tid >> 3, c4 = (tid & 7) * 4;
    f32x4 v = *reinterpret_cast<const f32x4*>(&W[(size_t)(k0 + row) * N + n0 + c4]);
    t[row][c4 + 0] = v[0];
    t[row][c4 + 1] = v[1];
    t[row][c4 + 2] = v[2];
    t[row][c4 + 3] = v[3];
    __syncthreads();
    s16x4 o;
    o[0] = (short)f2bf(t[c4 + 0][row]);
    o[1] = (short)f2bf(t[c4 + 1][row]);
    o[2] = (short)f2bf(t[c4 + 2][row]);
    o[3] = (short)f2bf(t[c4 + 3][row]);
    *reinterpret_cast<s16x4*>(&Wt[(size_t)(n0 + row) * K + k0 + c4]) = o;
}

// ====== 128x128 tile MFMA GEMM, BK=64 single-buffer gload_lds, XOR-swizzled LDS (R7/R14) ======
// LDS [128][64] linear. Swizzle: stored col-byte = logical ^ ((row&7)<<4), applied on the
// pre-swizzled GLOBAL source + inverted on the ds_read address -> conflict-free b128 reads.
// MODE 0: C = A @ Bt^T + bias -> Cout (f32). MODE 1: scatter QKV bf16 (Q pre-scaled 0.125).
template <int MODE>
__global__ __launch_bounds__(256, 4)
void gemm_kernel(const unsigned short* __restrict__ A,
                 const unsigned short* __restrict__ Bt,
                 const float* __restrict__ bias,
                 float* __restrict__ Cout,
                 unsigned short* __restrict__ Qo,
                 unsigned short* __restrict__ Ko,
                 unsigned short* __restrict__ Vto,
                 int M, int N, int Kd) {
    __shared__ unsigned short As[128 * 64];
    __shared__ unsigned short Bs[128 * 64];
    const int tid = threadIdx.x;
    const int wave = tid >> 6, lane = tid & 63;
    const int l15 = lane & 15, lhi = lane >> 4;
    const int wm = wave >> 1, wn = wave & 1;
    const int m0 = blockIdx.x * 128, n0 = blockIdx.y * 128;

    f32x4 acc[4][4];
#pragma unroll
    for (int i = 0; i < 4; i++)
#pragma unroll
        for (int j = 0; j < 4; j++) acc[i][j] = f32x4{0.f, 0.f, 0.f, 0.f};

    const int r0 = tid >> 3;
    const int cswz = (((tid & 7) ^ (r0 & 7)) << 3);
    const unsigned short* Ap = &A[(size_t)(m0 + r0) * Kd + cswz];
    const unsigned short* Bp = &Bt[(size_t)(n0 + r0) * Kd + cswz];
    const size_t K32 = (size_t)32 * Kd;
    const int csw0 = (lhi * 8) ^ ((l15 & 7) << 3);

    for (int k0 = 0; k0 < Kd; k0 += 64) {
#pragma unroll
        for (int blk = 0; blk < 4; blk++) {
            gload16(Ap + blk * K32 + k0, &As[blk * 2048 + tid * 8]);
            gload16(Bp + blk * K32 + k0, &Bs[blk * 2048 + tid * 8]);
        }
        __syncthreads();   // drains vmcnt(0): buffer ready

        bf16x8 av[2][4], bv[2][4];
#pragma unroll
        for (int ks = 0; ks < 2; ks++)
#pragma unroll
            for (int i = 0; i < 4; i++) {
                av[ks][i] = *reinterpret_cast<const bf16x8*>(
                    &As[(wm * 64 + i * 16 + l15) * 64 + (ks * 32 ^ csw0)]);
                bv[ks][i] = *reinterpret_cast<const bf16x8*>(
                    &Bs[(wn * 64 + i * 16 + l15) * 64 + (ks * 32 ^ csw0)]);
            }
#pragma unroll
        for (int ks = 0; ks < 2; ks++)
#pragma unroll
            for (int i = 0; i < 4; i++)
#pragma unroll
                for (int j = 0; j < 4; j++)
                    acc[i][j] = __builtin_amdgcn_mfma_f32_16x16x32_bf16(av[ks][i], bv[ks][j],
                                                                        acc[i][j], 0, 0, 0);
        __syncthreads();
    }

    // epilogue: D[row=(lane>>4)*4+r][col=lane&15] per 16x16 fragment
#pragma unroll
    for (int j = 0; j < 4; j++) {
        const int col = n0 + wn * 64 + j * 16 + l15;
        const float bv = bias[col];
#pragma unroll
        for (int i = 0; i < 4; i++) {
            const int rbase = m0 + wm * 64 + i * 16 + lhi * 4;
#pragma unroll
            for (int r = 0; r < 4; r++) {
                const int row = rbase + r;
                const float oval = acc[i][j][r] + bv;
                if (MODE == 0) {
                    Cout[(size_t)row * N + col] = oval;
                } else {
                    const int sel = col >> 10, c1 = col & 1023;
                    const int h = c1 >> 6, d = c1 & 63;
                    const int b = row >> 11, t = row & 2047;
                    if (sel == 0)
                        Qo[(((size_t)(b * 16 + h)) * 2048 + t) * 64 + d] = f2bf(oval * 0.125f);
                    else if (sel == 1)
                        Ko[(((size_t)(b * 16 + h)) * 2048 + t) * 64 + d] = f2bf(oval);
                    else
                        Vto[(((size_t)(b * 16 + h)) * 64 + d) * 2048 + t] = f2bf(oval);
                }
            }
        }
    }
}

// ---------------- causal flash attention, swapped-MFMA layout, K prefetch ----------------
// 1 wave = 64 q rows (4 q-frags); block = 4 waves; grid = 512 (head = bid&63).
__global__ __launch_bounds__(256, 2)
void attn_kernel(const unsigned short* __restrict__ Q,
                 const unsigned short* __restrict__ Kg,
                 const unsigned short* __restrict__ Vt,
                 unsigned short* __restrict__ Aout) {
    __shared__ unsigned int Pl[4][16 * 36];     // per-wave P^T tile: [q=16][k=64] bf16, 144B rows
    const int tid = threadIdx.x, wave = tid >> 6, lane = tid & 63;
    const int l15 = lane & 15, lhi = lane >> 4;
    const int bid = blockIdx.x;
    const int head = bid & 63;
    const int j = bid >> 6;
    const int qb = (j < 4) ? j : (11 - j);       // complement pairing: qb(j)+qb(j+4)=7
    const int q0w = qb * 256 + wave * 64;
    const unsigned short* Qh = Q + (size_t)head * (2048 * 64);
    const unsigned short* Kh = Kg + (size_t)head * (2048 * 64);
    const unsigned short* Vh = Vt + (size_t)head * (64 * 2048);
    unsigned int* P = &Pl[wave][0];

    bf16x8 qfr[4][2];
#pragma unroll
    for (int qf = 0; qf < 4; qf++)
#pragma unroll
        for (int dh = 0; dh < 2; dh++)
            qfr[qf][dh] = *reinterpret_cast<const bf16x8*>(
                &Qh[(size_t)(q0w + qf * 16 + l15) * 64 + dh * 32 + lhi * 8]);

    f32x4 o[4][4];   // [df][qf], O^T[d=df*16+lhi*4+r][q=qf*16+l15]
#pragma unroll
    for (int df = 0; df < 4; df++)
#pragma unroll
        for (int qf = 0; qf < 4; qf++) o[df][qf] = f32x4{0.f, 0.f, 0.f, 0.f};
    float m[4] = {-1e30f, -1e30f, -1e30f, -1e30f};
    float l[4] = {0.f, 0.f, 0.f, 0.f};

#define LOADK(DST, kt)                                                                  \
    do {                                                                                \
        _Pragma("unroll") for (int kf = 0; kf < 4; kf++)                                \
            _Pragma("unroll") for (int dh = 0; dh < 2; dh++)                            \
                DST[kf][dh] = *reinterpret_cast<const bf16x8*>(                         \
                    &Kh[(size_t)((kt) + kf * 16 + l15) * 64 + dh * 32 + lhi * 8]);      \
    } while (0)

    const int ntiles = (q0w >> 6) + 1;
    bf16x8 ka[4][2], kb[4][2], vfr[4][2];
    LOADK(ka, 0);
    for (int t = 0; t < ntiles; ++t) {
        const int kt = t * 64;
        const bool masked = (t == ntiles - 1);
#pragma unroll
        for (int df = 0; df < 4; df++)
#pragma unroll
            for (int kc = 0; kc < 2; kc++)
                vfr[df][kc] = *reinterpret_cast<const bf16x8*>(
                    &Vh[(size_t)(df * 16 + l15) * 2048 + kt + kc * 32 + lhi * 8]);
        const int ktn = masked ? kt : kt + 64;
        LOADK(kb, ktn);

#pragma unroll
        for (int qf = 0; qf < 4; qf++) {
            f32x4 s[4];
#pragma unroll
            for (int kf = 0; kf < 4; kf++) {
                s[kf] = __builtin_amdgcn_mfma_f32_16x16x32_bf16(ka[kf][0], qfr[qf][0],
                                                                f32x4{0.f, 0.f, 0.f, 0.f}, 0, 0, 0);
                s[kf] = __builtin_amdgcn_mfma_f32_16x16x32_bf16(ka[kf][1], qfr[qf][1], s[kf], 0, 0, 0);
            }
            if (masked) {
#pragma unroll
                for (int kf = 0; kf < 4; kf++)
#pragma unroll
                    for (int r = 0; r < 4; r++)
                        if (kf * 16 + lhi * 4 + r > qf * 16 + l15) s[kf][r] = -1e30f;
            }
            float tm = s[0][0];
#pragma unroll
            for (int kf = 0; kf < 4; kf++)
#pragma unroll
                for (int r = 0; r < 4; r++) tm = fmaxf(tm, s[kf][r]);
            tm = fmaxf(tm, __shfl_xor(tm, 16));
            tm = fmaxf(tm, __shfl_xor(tm, 32));
            const float mn = fmaxf(m[qf], tm);
            const float corr = __expf(m[qf] - mn);
            m[qf] = mn;
            float rs = 0.f;
#pragma unroll
            for (int kf = 0; kf < 4; kf++)
#pragma unroll
                for (int r = 0; r < 4; r++) {
                    const float p = __expf(s[kf][r] - mn);
                    s[kf][r] = p;
                    rs += p;
                }
            rs += __shfl_xor(rs, 16);
            rs += __shfl_xor(rs, 32);
            l[qf] = l[qf] * corr + rs;
#pragma unroll
            for (int df = 0; df < 4; df++)
#pragma unroll
                for (int r = 0; r < 4; r++) o[df][qf][r] *= corr;

#pragma unroll
            for (int kf = 0; kf < 4; kf++) {
                P[l15 * 36 + kf * 8 + lhi * 2 + 0] = pack2bf(s[kf][0], s[kf][1]);
                P[l15 * 36 + kf * 8 + lhi * 2 + 1] = pack2bf(s[kf][2], s[kf][3]);
            }
            asm volatile("s_waitcnt lgkmcnt(0)" ::: "memory");
            bf16x8 pb0 = *reinterpret_cast<const bf16x8*>(&P[l15 * 36 + 0 * 16 + lhi * 4]);
            bf16x8 pb1 = *reinterpret_cast<const bf16x8*>(&P[l15 * 36 + 1 * 16 + lhi * 4]);
#pragma unroll
            for (int df = 0; df < 4; df++) {
                o[df][qf] = __builtin_amdgcn_mfma_f32_16x16x32_bf16(vfr[df][0], pb0, o[df][qf], 0, 0, 0);
                o[df][qf] = __builtin_amdgcn_mfma_f32_16x16x32_bf16(vfr[df][1], pb1, o[df][qf], 0, 0, 0);
            }
        }
#pragma unroll
        for (int kf = 0; kf < 4; kf++)
#pragma unroll
            for (int dh = 0; dh < 2; dh++) ka[kf][dh] = kb[kf][dh];
    }
#undef LOADK

    const int b = head >> 4, h = head & 15;
#pragma unroll
    for (int qf = 0; qf < 4; qf++) {
        const float inv = 1.0f / l[qf];
        unsigned short* op = Aout + ((size_t)(b * 2048 + q0w + qf * 16 + l15)) * 1024 + h * 64;
#pragma unroll
        for (int df = 0; df < 4; df++) {
            *reinterpret_cast<unsigned*>(&op[df * 16 + lhi * 4]) =
                pack2bf(o[df][qf][0] * inv, o[df][qf][1] * inv);
            *reinterpret_cast<unsigned*>(&op[df * 16 + lhi * 4 + 2]) =
                pack2bf(o[df][qf][2] * inv, o[df][qf][3] * inv);
        }
    }
}

extern "C" void kernel_launch(void* const* d_in, const int* in_sizes, int n_in,
                              void* d_out, int out_size, void* d_ws, size_t ws_size,
                              hipStream_t stream) {
    const float* x     = (const float*)d_in[0];
    const float* Wattn = (const float*)d_in[1];
    const float* battn = (const float*)d_in[2];
    const float* Wproj = (const float*)d_in[3];
    const float* bproj = (const float*)d_in[4];
    float* out = (float*)d_out;

    unsigned short* ws = (unsigned short*)d_ws;
    const size_t HS = (size_t)4 * 16 * 2048 * 64;
    unsigned short* Qb  = ws;
    unsigned short* Kb  = Qb + HS;
    unsigned short* Vtb = Kb + HS;
    unsigned short* Ab  = Vtb + HS;
    unsigned short* Wta = Ab + HS;
    unsigned short* Wtp = Wta + (size_t)3072 * 1024;
    unsigned short* xb  = Wtp + (size_t)1024 * 1024;

    prep_kernel<<<12288, 256, 0, stream>>>(x, xb, Wattn, Wta, Wproj, Wtp);
    gemm_kernel<1><<<dim3(64, 24), 256, 0, stream>>>(xb, Wta, battn, nullptr, Qb, Kb, Vtb,
                                                     8192, 3072, 1024);
    attn_kernel<<<512, 256, 0, stream>>>(Qb, Kb, Vtb, Ab);
    gemm_kernel<0><<<dim3(64, 8), 256, 0, stream>>>(Ab, Wtp, bproj, out, nullptr, nullptr, nullptr,
                                                    8192, 1024, 1024);
}